// Round 11
// baseline (164.379 us; speedup 1.0000x reference)
//
#include <hip/hip_runtime.h>
#include <hip/hip_bf16.h>
#include <math.h>

typedef __bf16 bf16x8 __attribute__((ext_vector_type(8)));
typedef float  f32x4  __attribute__((ext_vector_type(4)));

#define M_DIM 16384
#define N_DIM 512
#define K_DIM 512

// async global->LDS DMA, 16 B/lane; LDS dest = wave-uniform base + lane*16
__device__ inline void gl_lds16f(const float* g, float* l) {
    __builtin_amdgcn_global_load_lds(
        (const __attribute__((address_space(1))) void*)g,
        (__attribute__((address_space(3))) void*)l, 16, 0, 0);
}

// Single fused kernel. Tile 128 gm x 64 gn, 4 waves (each 64gm x 64gn via
// acc[4][2]), grid 1024 = 4 blocks/CU (LDS exactly 40960 B).
// A-operand = W (gn), B-operand = x (gm)  => thread's 4 acc elems are 4
// consecutive gn => float4 epilogue stores.
// x: fp32 staged by global_load_lds with 16-chunk XOR swizzle on the GLOBAL
//    address (LDS dest order fixed); frags read as 2x ds_read_b128 + cvt.
// W: bf16 staged by VALU (tiny), same 8-chunk XOR layout as R10.
// I_in table: 64 entries held in lane registers, gathered via ds_bpermute.
__global__ __launch_bounds__(256, 4)
void snn_fused_kernel(const float* __restrict__ x, const float* __restrict__ W,
                      const float* __restrict__ gNa_p, const float* __restrict__ gK_p,
                      const float* __restrict__ gL_p, float* __restrict__ out)
{
    __shared__ float  sX[128 * 64];   // 32 KB fp32 x-tile
    __shared__ __bf16 sW[64 * 64];    //  8 KB bf16 W-tile  -> 40960 B total

    const int tid = threadIdx.x;

    // XCD swizzle: each XCD owns 16 bm tiles (16*128 rows * 2 KB fp32 = 4 MB
    // of x = its L2); consecutive slots sweep all 8 bn for one bm.
    const int id   = blockIdx.x;            // 0..1023
    const int xcd  = id & 7;
    const int slot = id >> 3;               // 0..127
    const int bm   = xcd * 16 + (slot >> 3);    // 0..127
    const int bn   = slot & 7;                  // 0..7

    const int wv   = tid >> 6;
    const int ln   = tid & 63;
    const int lr   = ln & 15;
    const int quad = ln >> 4;

    // ---- x DMA mapping: fp32 row = 64 floats = 16 chunks of 16 B.
    // Wave covers 4 rows/issue: rw=ln>>4, chunk slot ch=ln&15.
    // Global chunk fetched = ch ^ (row & 15); row&15 = (4j+rw)&15 = (4j&15)^rw.
    const int rw = ln >> 4;
    const int ch = ln & 15;
    const float* xRow = x + ((long)bm * 128 + 32 * wv + rw) * K_DIM;

    // ---- W staging mapping: thread t -> row=t&63, chunk pair (t>>6)*2
    // (chunks of 8 bf16). Slot for global chunk c = c ^ (row & 7).
    const int wr  = tid & 63;
    const int wcp = (tid >> 6) * 2;
    const float* wRow = W + ((long)bn * 64 + wr) * K_DIM + wcp * 8;
    __bf16* sWr = sW + wr * 64;
    const int ws0 = (wcp ^ (wr & 7)) * 8;
    const int ws1 = ((wcp + 1) ^ (wr & 7)) * 8;

    // ---- 64-entry I_in(V) table in lane registers, V in [-4,4] ----
    float tblv;
    {
        const float gNa = *gNa_p, gK = *gK_p, gL = *gL_p;
        const float V = -4.0f + (8.0f / 63.0f) * (float)ln;
        const float am = 0.1f * (V + 40.0f) / (1.0f - expf(-(V + 40.0f) * 0.1f));
        const float bmg = 4.0f * expf(-(V + 65.0f) * (1.0f / 18.0f));
        const float ah = 0.07f * expf(-(V + 65.0f) * 0.05f);
        const float bh = 1.0f / (1.0f + expf(-(V + 35.0f) * 0.1f));
        const float an = 0.01f * (V + 55.0f) / (1.0f - expf(-(V + 55.0f) * 0.1f));
        const float bng = 0.125f * expf(-(V + 65.0f) * 0.0125f);
        const float m = 0.05f + 0.1f * (am * 0.95f - bmg * 0.05f);
        const float h = 0.60f + 0.1f * (ah * 0.40f - bh * 0.60f);
        const float n = 0.32f + 0.1f * (an * 0.68f - bng * 0.32f);
        tblv = gNa * m * m * m * h * (V - 50.0f)
             + gK * (n * n) * (n * n) * (V + 77.0f)
             + gL * (V + 54.4f) + V;
    }

    f32x4 acc[4][2] = {};   // [gn frag f][gm frag g]

    // ---- stage tile kt: W vmem loads first, then x DMA issues, then W cvt+write
    auto stage = [&](int kt) {
        float4 w0 = *(const float4*)(wRow + kt);
        float4 w1 = *(const float4*)(wRow + kt + 4);
        float4 w2 = *(const float4*)(wRow + kt + 8);
        float4 w3 = *(const float4*)(wRow + kt + 12);
        #pragma unroll
        for (int j = 0; j < 8; ++j) {
            const int cx = (ch ^ rw ^ ((4 * j) & 15)) * 4;   // swizzled float offset
            gl_lds16f(xRow + (long)(4 * j) * K_DIM + kt + cx,
                      sX + (32 * wv + 4 * j) * 64);
        }
        bf16x8 lo = { (__bf16)w0.x, (__bf16)w0.y, (__bf16)w0.z, (__bf16)w0.w,
                      (__bf16)w1.x, (__bf16)w1.y, (__bf16)w1.z, (__bf16)w1.w };
        bf16x8 hi = { (__bf16)w2.x, (__bf16)w2.y, (__bf16)w2.z, (__bf16)w2.w,
                      (__bf16)w3.x, (__bf16)w3.y, (__bf16)w3.z, (__bf16)w3.w };
        *(bf16x8*)(sWr + ws0) = lo;
        *(bf16x8*)(sWr + ws1) = hi;
    };

    stage(0);
    __syncthreads();   // tile 0 resident

    for (int t = 0; t < 8; ++t) {
        #pragma unroll
        for (int kk = 0; kk < 2; ++kk) {
            const int cidx = quad + 4 * kk;
            const int slw  = (cidx ^ (lr & 7)) * 8;     // sW slot (8 chunks)
            bf16x8 aw[4], bx[2];
            #pragma unroll
            for (int f = 0; f < 4; ++f)
                aw[f] = *(const bf16x8*)(sW + (f * 16 + lr) * 64 + slw);
            #pragma unroll
            for (int g = 0; g < 2; ++g) {
                const int row = 32 * wv + g * 16 + lr;
                const int s0  = ((2 * cidx)     ^ lr) * 4;  // sX slots (16 chunks)
                const int s1  = ((2 * cidx + 1) ^ lr) * 4;
                float4 p0 = *(const float4*)(sX + row * 64 + s0);
                float4 p1 = *(const float4*)(sX + row * 64 + s1);
                bf16x8 b = { (__bf16)p0.x, (__bf16)p0.y, (__bf16)p0.z, (__bf16)p0.w,
                             (__bf16)p1.x, (__bf16)p1.y, (__bf16)p1.z, (__bf16)p1.w };
                bx[g] = b;
            }
            #pragma unroll
            for (int f = 0; f < 4; ++f)
                #pragma unroll
                for (int g = 0; g < 2; ++g)
                    acc[f][g] = __builtin_amdgcn_mfma_f32_16x16x32_bf16(
                        aw[f], bx[g], acc[f][g], 0, 0, 0);
        }
        if (t < 7) {
            __syncthreads();          // reads of tile t done
            stage((t + 1) * 64);
            __syncthreads();          // tile t+1 resident
        }
    }

    // ---- epilogue: bpermute-lerp HH, float4 stores (4 consecutive gn) ----
    float* outS = out;
    float* outV = out + (long)M_DIM * N_DIM;
    float* outWp = out + 2L * M_DIM * N_DIM;
    const int tbits = __float_as_int(tblv);

    #pragma unroll
    for (int f = 0; f < 4; ++f) {
        const int gn4 = bn * 64 + f * 16 + quad * 4;
        #pragma unroll
        for (int g = 0; g < 2; ++g) {
            const long gm  = (long)bm * 128 + 32 * wv + g * 16 + lr;
            const long idx = gm * N_DIM + gn4;
            f32x4 vS, vV, vW;
            #pragma unroll
            for (int i = 0; i < 4; ++i) {
                const float V = acc[f][g][i];
                float u = (V + 4.0f) * (63.0f / 8.0f);
                u = fminf(fmaxf(u, 0.0f), 62.999f);
                const int   iu = (int)u;
                const float fr = u - (float)iu;
                const float t0 = __int_as_float(
                    __builtin_amdgcn_ds_bpermute(iu << 2, tbits));
                const float t1 = __int_as_float(
                    __builtin_amdgcn_ds_bpermute((iu << 2) + 4, tbits));
                const float I_in = t0 + fr * (t1 - t0);
                const float v_new = -65.0f + I_in * 0.005f;
                const float spike = (v_new >= -50.0f) ? 1.0f : 0.0f;
                vS[i] = spike;
                vW[i] = (0.5f * (v_new + 65.0f) + 0.1f * spike) * 0.001f;
                vV[i] = (spike > 0.5f) ? -65.0f : v_new;
            }
            *(f32x4*)(outS + idx) = vS;
            *(f32x4*)(outV + idx) = vV;
            *(f32x4*)(outWp + idx) = vW;
        }
    }
}

extern "C" void kernel_launch(void* const* d_in, const int* in_sizes, int n_in,
                              void* d_out, int out_size, void* d_ws, size_t ws_size,
                              hipStream_t stream) {
    const float* x   = (const float*)d_in[0];
    const float* W   = (const float*)d_in[1];
    const float* gNa = (const float*)d_in[2];
    const float* gK  = (const float*)d_in[3];
    const float* gL  = (const float*)d_in[4];
    float* out = (float*)d_out;

    dim3 grid((M_DIM / 128) * (N_DIM / 64));   // 1024 blocks = 4/CU, perfect packing
    dim3 block(256);
    hipLaunchKernelGGL(snn_fused_kernel, grid, block, 0, stream,
                       x, W, gNa, gK, gL, out);
}